// Round 5
// baseline (363.098 us; speedup 1.0000x reference)
//
#include <hip/hip_runtime.h>

#define BB 8
#define C 64
#define HH 128
#define WW 128
#define HW (HH*WW)

#define TS 72        // LDS channel stride (ushorts): 144B rows, 16B aligned
#define NPX 324      // 18*18 halo tile pixels

typedef __attribute__((ext_vector_type(8))) short short8;
typedef __attribute__((ext_vector_type(4))) short short4v;
typedef __attribute__((ext_vector_type(4))) float f32x4;

__device__ inline unsigned short f2bf(float f) {
    union { float f; unsigned u; } v; v.f = f;
    unsigned r = v.u + 0x7fff + ((v.u >> 16) & 1);   // RNE
    return (unsigned short)(r >> 16);
}
__device__ inline float bf2f(unsigned short h) {
    union { unsigned u; float f; } v; v.u = ((unsigned)h) << 16;
    return v.f;
}

// ---------------------------------------------------------------------------
// Prep: wb[p][row][ci] bf16 for conv0/convf (row=oc) and wb3 (row'=j*64+oc);
// b3r[j][oc]; zero m.
// ---------------------------------------------------------------------------
__global__ __launch_bounds__(256) void prep_kernel(
    const float* __restrict__ w0, const float* __restrict__ wf,
    const float* __restrict__ w3, const float* __restrict__ b3,
    unsigned short* __restrict__ wb0, unsigned short* __restrict__ wbf,
    unsigned short* __restrict__ wb3, float* __restrict__ b3r,
    float* __restrict__ m)
{
    const int t = blockIdx.x * 256 + threadIdx.x;
    for (int i = t; i < C*C*9; i += 32*256) {
        int p = i % 9; int rest = i / 9; int ci = rest % C; int oc = rest / C;
        wb0[(p*C + oc)*C + ci] = f2bf(w0[i]);
        wbf[(p*C + oc)*C + ci] = f2bf(wf[i]);
    }
    for (int i = t; i < 9*C*C; i += 32*256) {        // dst: ((j*64+oc)*64+k)
        int j = i >> 12, oc = (i >> 6) & 63, k = i & 63;
        wb3[i] = f2bf(w3[(oc*9 + j)*C + k]);
    }
    for (int i = t; i < 9*C; i += 32*256) {          // b3r[j*64+oc] = b3[oc*9+j]
        int j = i >> 6, oc = i & 63;
        b3r[i] = b3[oc*9 + j];
    }
    for (int i = t; i < BB*C; i += 32*256) m[i] = 0.f;
}

// ---------------------------------------------------------------------------
// conv0: MFMA implicit-GEMM, TRANSPOSED (M=oc, N=pixels). In: x fp32 NCHW.
// Out: x0 bf16 NHWC (+bias) via dwordx2 stores (C/D col=pixel, row=oc).
// ---------------------------------------------------------------------------
__global__ __launch_bounds__(256, 3) void conv0_kernel(
    const float* __restrict__ x,
    const unsigned short* __restrict__ wb,   // [9][64][64] (row=oc, k=ci)
    const float* __restrict__ bias,
    unsigned short* __restrict__ x0g)        // [B,H,W,C] bf16
{
    __shared__ unsigned short tile[NPX*TS];  // 46.7 KB
    const int b  = blockIdx.z;
    const int h0 = blockIdx.y * 16;
    const int w0 = blockIdx.x * 16;
    const int t  = threadIdx.x;

    {
        const int pxi = t & 31, g = t >> 5;
        for (int px = pxi; px < NPX; px += 32) {
            int th = px / 18, tw = px - th*18;
            int gh = h0 + th - 1, gw = w0 + tw - 1;
            short8 v = {0,0,0,0,0,0,0,0};
            if ((unsigned)gh < HH && (unsigned)gw < WW) {
                const float* sp = x + ((size_t)(b*C + g*8)*HW + gh*WW + gw);
#pragma unroll
                for (int k = 0; k < 8; ++k) v[k] = (short)f2bf(sp[k*HW]);
            }
            *(short8*)&tile[px*TS + g*8] = v;
        }
    }
    __syncthreads();

    const int wid = t >> 6, ln = t & 63;
    const int l15 = ln & 15, q = ln >> 4;

    f32x4 acc[4][4];   // [nt(pixel rows)][mt(oc)]
#pragma unroll
    for (int nt = 0; nt < 4; ++nt)
#pragma unroll
        for (int mt = 0; mt < 4; ++mt) acc[nt][mt] = (f32x4){0.f,0.f,0.f,0.f};

#pragma unroll
    for (int p = 0; p < 9; ++p) {
        const int dh = p / 3, dw = p % 3;
#pragma unroll
        for (int ks = 0; ks < 2; ++ks) {
            short8 af[4];   // weights: A[m=oc][k=ci]
#pragma unroll
            for (int mt = 0; mt < 4; ++mt)
                af[mt] = *(const short8*)&wb[((size_t)(p*C) + mt*16 + l15)*C + ks*32 + q*8];
            short8 bf[4];   // pixels: B[k=ci][n=px]
#pragma unroll
            for (int nt = 0; nt < 4; ++nt)
                bf[nt] = *(const short8*)&tile[((wid*4+nt+dh)*18 + l15 + dw)*TS + ks*32 + q*8];
#pragma unroll
            for (int nt = 0; nt < 4; ++nt)
#pragma unroll
                for (int mt = 0; mt < 4; ++mt)
                    acc[nt][mt] = __builtin_amdgcn_mfma_f32_16x16x32_bf16(
                        af[mt], bf[nt], acc[nt][mt], 0, 0, 0);
        }
    }

    // epilogue: col=pixel(l15), row=oc(q*4+reg) -> NHWC dwordx2 stores
#pragma unroll
    for (int nt = 0; nt < 4; ++nt) {
        const int hh = h0 + wid*4 + nt;
        const size_t base = ((size_t)(b*HW) + hh*WW + w0 + l15)*C;
#pragma unroll
        for (int mt = 0; mt < 4; ++mt) {
            const int oc0 = mt*16 + q*4;
            const float4 bv = *(const float4*)&bias[oc0];
            unsigned u0 = (unsigned)f2bf(acc[nt][mt][0] + bv.x)
                        | ((unsigned)f2bf(acc[nt][mt][1] + bv.y) << 16);
            unsigned u1 = (unsigned)f2bf(acc[nt][mt][2] + bv.z)
                        | ((unsigned)f2bf(acc[nt][mt][3] + bv.w) << 16);
            uint2 uu; uu.x = u0; uu.y = u1;
            *(uint2*)&x0g[base + oc0] = uu;
        }
    }
}

// ---------------------------------------------------------------------------
// Per-(b,c) spatial mean of x0 (NHWC bf16). 128 blocks, atomicAdd partials.
// ---------------------------------------------------------------------------
__global__ __launch_bounds__(256) void mean_kernel(
    const unsigned short* __restrict__ x0, float* __restrict__ m)
{
    const int b = blockIdx.x >> 4, slice = blockIdx.x & 15;
    const int t = threadIdx.x;
    const int pxi = t >> 3, g = t & 7;
    const unsigned short* base = x0 + ((size_t)b*HW + slice*1024)*C + g*8;
    float s[8];
#pragma unroll
    for (int k = 0; k < 8; ++k) s[k] = 0.f;
    for (int it = 0; it < 32; ++it) {
        short8 v = *(const short8*)&base[(size_t)(it*32 + pxi)*C];
#pragma unroll
        for (int k = 0; k < 8; ++k) s[k] += bf2f((unsigned short)v[k]);
    }
    __shared__ float red[32][64];
#pragma unroll
    for (int k = 0; k < 8; ++k) red[pxi][g*8+k] = s[k];
    __syncthreads();
    if (t < 64) {
        float acc = 0.f;
        for (int i = 0; i < 32; ++i) acc += red[i][t];
        atomicAdd(&m[b*C + t], acc * (1.f/(float)HW));
    }
}

// ---------------------------------------------------------------------------
// dw_eca: depthwise 3x3 + ECA attention, LDS-free, one thread per pixel.
// Reads x0 NHWC (L1/L2-served), writes aout NHWC bf16.
// ---------------------------------------------------------------------------
__global__ __launch_bounds__(256, 4) void dw_eca_kernel(
    const unsigned short* __restrict__ x0,
    const float* __restrict__ w1, const float* __restrict__ b1,
    const float* __restrict__ w2, const float* __restrict__ b2,
    const float* __restrict__ m,
    unsigned short* __restrict__ aout)
{
    const int tg = blockIdx.x * 256 + threadIdx.x;
    const int b = tg >> 14, px = tg & 16383;
    const int h = px >> 7, w = px & 127;
    const unsigned short* xb = x0 + (size_t)(b*HW)*C;
    const float w2a = w2[0], w2b = w2[1], w2c = w2[2], b2v = b2[0];

#pragma unroll
    for (int g = 0; g < 8; ++g) {
        float dw8[8];
#pragma unroll
        for (int k = 0; k < 8; ++k) dw8[k] = 0.f;
#pragma unroll
        for (int j = 0; j < 9; ++j) {
            const int nh = h + j/3 - 1, nw = w + j%3 - 1;
            short8 v = {0,0,0,0,0,0,0,0};
            if ((unsigned)nh < HH && (unsigned)nw < WW)
                v = *(const short8*)&xb[(size_t)(nh*WW + nw)*C + g*8];
#pragma unroll
            for (int k = 0; k < 8; ++k)
                dw8[k] = fmaf(w1[(g*8+k)*9 + j], bf2f((unsigned short)v[k]), dw8[k]);
        }
        short8 o;
#pragma unroll
        for (int k = 0; k < 8; ++k) {
            const int c = g*8 + k;
            const float mc = m[b*C + c];
            const float mp = (c > 0)  ? m[b*C + c - 1] : 0.f;
            const float mn = (c < 63) ? m[b*C + c + 1] : 0.f;
            const float att = fmaf(w2a, mp, fmaf(w2b, mc, fmaf(w2c, mn, b2v)));
            o[k] = (short)f2bf(dw8[k] + b1[c] + att);
        }
        *(short8*)&aout[(size_t)(b*HW + px)*C + g*8] = o;
    }
}

// ---------------------------------------------------------------------------
// dynconv: transposed GEMM (M=576 filter rows, N=256 pixels, K=64) + per-pixel
// dynamic conv + leaky. A=wb3 (global), B=aout (global), patches from x0 tile
// (LDS, 46.7 KB -> 3 blocks/CU). Consume = aligned ds_read_b64.
// ---------------------------------------------------------------------------
__global__ __launch_bounds__(256, 3) void dynconv_kernel(
    const unsigned short* __restrict__ x0,
    const unsigned short* __restrict__ aout,
    const unsigned short* __restrict__ wb3,  // [(j*64+oc)][k]
    const float* __restrict__ b3r,           // [j*64+oc]
    unsigned short* __restrict__ yg)
{
    __shared__ unsigned short tile[NPX*TS];
    const int b  = blockIdx.z;
    const int h0 = blockIdx.y * 16;
    const int w0 = blockIdx.x * 16;
    const int t  = threadIdx.x;

    {
        const int pxi = t & 31, g = t >> 5;
        for (int px = pxi; px < NPX; px += 32) {
            int th = px / 18, tw = px - th*18;
            int gh = h0 + th - 1, gw = w0 + tw - 1;
            short8 v = {0,0,0,0,0,0,0,0};
            if ((unsigned)gh < HH && (unsigned)gw < WW)
                v = *(const short8*)&x0[((size_t)(b*HW) + gh*WW + gw)*C + g*8];
            *(short8*)&tile[px*TS + g*8] = v;
        }
    }
    __syncthreads();

    const int wid = t >> 6, ln = t & 63;
    const int l15 = ln & 15, q = ln >> 4;
    const int rl0 = wid*4;

    // persistent pixel B-fragments: B[k=ch][n=px], 8 consecutive ch of own pixel
    short8 pfrag[4][2];
#pragma unroll
    for (int nt = 0; nt < 4; ++nt) {
        const size_t pbase = ((size_t)(b*HW) + (h0+rl0+nt)*WW + w0 + l15)*C;
#pragma unroll
        for (int ks = 0; ks < 2; ++ks)
            pfrag[nt][ks] = *(const short8*)&aout[pbase + ks*32 + q*8];
    }

    f32x4 yac[4][4];   // [nt][ocg]
#pragma unroll
    for (int nt = 0; nt < 4; ++nt)
#pragma unroll
        for (int og = 0; og < 4; ++og) yac[nt][og] = (f32x4){0.f,0.f,0.f,0.f};

    for (int dh = 0; dh < 3; ++dh) {
        for (int dw = 0; dw < 3; ++dw) {
            const int j = dh*3 + dw;
#pragma unroll
            for (int og = 0; og < 4; ++og) {
                const f32x4 seed = *(const f32x4*)&b3r[j*64 + og*16 + q*4];
                const size_t abase = ((size_t)(j*64 + og*16 + l15))*C;
                const short8 a0 = *(const short8*)&wb3[abase + q*8];
                const short8 a1 = *(const short8*)&wb3[abase + 32 + q*8];
#pragma unroll
                for (int nt = 0; nt < 4; ++nt) {
                    f32x4 fil = __builtin_amdgcn_mfma_f32_16x16x32_bf16(
                        a0, pfrag[nt][0], seed, 0, 0, 0);
                    fil = __builtin_amdgcn_mfma_f32_16x16x32_bf16(
                        a1, pfrag[nt][1], fil, 0, 0, 0);
                    const short4v pv = *(const short4v*)
                        &tile[((rl0+nt+dh)*18 + l15 + dw)*TS + og*16 + q*4];
#pragma unroll
                    for (int reg = 0; reg < 4; ++reg)
                        yac[nt][og][reg] = fmaf(fil[reg],
                            bf2f((unsigned short)pv[reg]), yac[nt][og][reg]);
                }
            }
        }
    }

    // epilogue: leaky + NHWC bf16 dwordx2 stores (col=pixel, row=oc)
#pragma unroll
    for (int nt = 0; nt < 4; ++nt) {
        const size_t base = ((size_t)(b*HW) + (h0+rl0+nt)*WW + w0 + l15)*C;
#pragma unroll
        for (int og = 0; og < 4; ++og) {
            f32x4 v = yac[nt][og];
#pragma unroll
            for (int reg = 0; reg < 4; ++reg)
                v[reg] = (v[reg] >= 0.f) ? v[reg] : 0.2f * v[reg];
            unsigned u0 = (unsigned)f2bf(v[0]) | ((unsigned)f2bf(v[1]) << 16);
            unsigned u1 = (unsigned)f2bf(v[2]) | ((unsigned)f2bf(v[3]) << 16);
            uint2 uu; uu.x = u0; uu.y = u1;
            *(uint2*)&yg[base + og*16 + q*4] = uu;
        }
    }
}

// ---------------------------------------------------------------------------
// convf: MFMA implicit-GEMM (M=pixels, N=oc). In: y bf16 NHWC.
// Out: fp32 NCHW (+bias+residual) via float4 stores.
// ---------------------------------------------------------------------------
__global__ __launch_bounds__(256, 3) void convf_kernel(
    const unsigned short* __restrict__ yg,
    const unsigned short* __restrict__ wb,   // [9][64][64]
    const float* __restrict__ bias,
    const float* __restrict__ res,
    float* __restrict__ outg)
{
    __shared__ unsigned short tile[NPX*TS];
    const int b  = blockIdx.z;
    const int h0 = blockIdx.y * 16;
    const int w0 = blockIdx.x * 16;
    const int t  = threadIdx.x;

    {
        const int pxi = t & 31, g = t >> 5;
        for (int px = pxi; px < NPX; px += 32) {
            int th = px / 18, tw = px - th*18;
            int gh = h0 + th - 1, gw = w0 + tw - 1;
            short8 v = {0,0,0,0,0,0,0,0};
            if ((unsigned)gh < HH && (unsigned)gw < WW)
                v = *(const short8*)&yg[((size_t)(b*HW) + gh*WW + gw)*C + g*8];
            *(short8*)&tile[px*TS + g*8] = v;
        }
    }
    __syncthreads();

    const int wid = t >> 6, ln = t & 63;
    const int l15 = ln & 15, q = ln >> 4;

    f32x4 acc[4][4];   // [mg(pixel rows)][nt(oc)]
#pragma unroll
    for (int mg = 0; mg < 4; ++mg)
#pragma unroll
        for (int nt = 0; nt < 4; ++nt) acc[mg][nt] = (f32x4){0.f,0.f,0.f,0.f};

#pragma unroll
    for (int p = 0; p < 9; ++p) {
        const int dh = p / 3, dw = p % 3;
#pragma unroll
        for (int ks = 0; ks < 2; ++ks) {
            short8 bfrag[4];
#pragma unroll
            for (int nt = 0; nt < 4; ++nt)
                bfrag[nt] = *(const short8*)&wb[((size_t)(p*C) + nt*16 + l15)*C + ks*32 + q*8];
            short8 afrag[4];
#pragma unroll
            for (int mg = 0; mg < 4; ++mg)
                afrag[mg] = *(const short8*)&tile[((wid*4+mg+dh)*18 + l15 + dw)*TS + ks*32 + q*8];
#pragma unroll
            for (int mg = 0; mg < 4; ++mg)
#pragma unroll
                for (int nt = 0; nt < 4; ++nt)
                    acc[mg][nt] = __builtin_amdgcn_mfma_f32_16x16x32_bf16(
                        afrag[mg], bfrag[nt], acc[mg][nt], 0, 0, 0);
        }
    }

#pragma unroll
    for (int mg = 0; mg < 4; ++mg) {
        const int hh = h0 + wid*4 + mg;
#pragma unroll
        for (int nt = 0; nt < 4; ++nt) {
            const int oc = nt*16 + l15;
            const float bv = bias[oc];
            const size_t base = (size_t)(b*C + oc)*HW + hh*WW + w0 + q*4;
            const float4 rv = *(const float4*)&res[base];
            float4 ov;
            ov.x = acc[mg][nt][0] + bv + rv.x;
            ov.y = acc[mg][nt][1] + bv + rv.y;
            ov.z = acc[mg][nt][2] + bv + rv.z;
            ov.w = acc[mg][nt][3] + bv + rv.w;
            *(float4*)&outg[base] = ov;
        }
    }
}

extern "C" void kernel_launch(void* const* d_in, const int* in_sizes, int n_in,
                              void* d_out, int out_size, void* d_ws, size_t ws_size,
                              hipStream_t stream) {
    const float* x  = (const float*)d_in[0];
    const float* w0 = (const float*)d_in[1];
    const float* b0 = (const float*)d_in[2];
    const float* w1 = (const float*)d_in[3];
    const float* b1 = (const float*)d_in[4];
    const float* w2 = (const float*)d_in[5];
    const float* b2 = (const float*)d_in[6];
    const float* w3 = (const float*)d_in[7];
    const float* b3 = (const float*)d_in[8];
    const float* wf = (const float*)d_in[9];
    const float* bf = (const float*)d_in[10];
    float* out = (float*)d_out;

    unsigned short* x0  = (unsigned short*)d_ws;            // [B,H,W,C] bf16
    unsigned short* y   = x0  + (size_t)BB*HW*C;            // [B,H,W,C] bf16
    unsigned short* ao  = y   + (size_t)BB*HW*C;            // [B,H,W,C] bf16
    float*          m   = (float*)(ao + (size_t)BB*HW*C);   // [B*C]
    unsigned short* wb0 = (unsigned short*)(m + BB*C);
    unsigned short* wbf = wb0 + 9*C*C;
    unsigned short* wb3 = wbf + 9*C*C;
    float*          b3r = (float*)(wb3 + 9*C*C);

    prep_kernel<<<32, 256, 0, stream>>>(w0, wf, w3, b3, wb0, wbf, wb3, b3r, m);
    conv0_kernel<<<dim3(8,8,8), 256, 0, stream>>>(x, wb0, b0, x0);
    mean_kernel<<<128, 256, 0, stream>>>(x0, m);
    dw_eca_kernel<<<512, 256, 0, stream>>>(x0, w1, b1, w2, b2, m, ao);
    dynconv_kernel<<<dim3(8,8,8), 256, 0, stream>>>(x0, ao, wb3, b3r, y);
    convf_kernel<<<dim3(8,8,8), 256, 0, stream>>>(y, wbf, bf, x, out);
}

// Round 6
// 252.698 us; speedup vs baseline: 1.4369x; 1.4369x over previous
//
#include <hip/hip_runtime.h>

#define BB 8
#define C 64
#define HH 128
#define WW 128
#define HW (HH*WW)

#define TS 72        // LDS channel stride (ushorts): 144B rows, 16B aligned
#define NPX 324      // 18*18 halo tile pixels

typedef __attribute__((ext_vector_type(8))) short short8;
typedef __attribute__((ext_vector_type(4))) short short4v;
typedef __attribute__((ext_vector_type(4))) float f32x4;

__device__ inline unsigned short f2bf(float f) {
    union { float f; unsigned u; } v; v.f = f;
    unsigned r = v.u + 0x7fff + ((v.u >> 16) & 1);   // RNE
    return (unsigned short)(r >> 16);
}
__device__ inline float bf2f(unsigned short h) {
    union { unsigned u; float f; } v; v.u = ((unsigned)h) << 16;
    return v.f;
}

// ---------------------------------------------------------------------------
// Prep: wb[p][row][ci] bf16 for conv0/convf (row=oc) and wb3 (row'=j*64+oc);
// b3r[j][oc]; zero m.
// ---------------------------------------------------------------------------
__global__ __launch_bounds__(256) void prep_kernel(
    const float* __restrict__ w0, const float* __restrict__ wf,
    const float* __restrict__ w3, const float* __restrict__ b3,
    unsigned short* __restrict__ wb0, unsigned short* __restrict__ wbf,
    unsigned short* __restrict__ wb3, float* __restrict__ b3r,
    float* __restrict__ m)
{
    const int t = blockIdx.x * 256 + threadIdx.x;
    for (int i = t; i < C*C*9; i += 32*256) {
        int p = i % 9; int rest = i / 9; int ci = rest % C; int oc = rest / C;
        wb0[(p*C + oc)*C + ci] = f2bf(w0[i]);
        wbf[(p*C + oc)*C + ci] = f2bf(wf[i]);
    }
    for (int i = t; i < 9*C*C; i += 32*256) {        // dst: ((j*64+oc)*64+k)
        int j = i >> 12, oc = (i >> 6) & 63, k = i & 63;
        wb3[i] = f2bf(w3[(oc*9 + j)*C + k]);
    }
    for (int i = t; i < 9*C; i += 32*256) {          // b3r[j*64+oc] = b3[oc*9+j]
        int j = i >> 6, oc = i & 63;
        b3r[i] = b3[oc*9 + j];
    }
    for (int i = t; i < BB*C; i += 32*256) m[i] = 0.f;
}

// ---------------------------------------------------------------------------
// conv0: MFMA implicit-GEMM, TRANSPOSED (M=oc, N=pixels). In: x fp32 NCHW.
// Out: x0 bf16 NHWC (+bias) via dwordx2 stores (C/D col=pixel, row=oc).
// NOTE: no min-waves launch_bounds arg — round 5's (256,3) capped VGPRs and
// caused spill-to-scratch (331 MB of scratch writes in dynconv).
// ---------------------------------------------------------------------------
__global__ __launch_bounds__(256) void conv0_kernel(
    const float* __restrict__ x,
    const unsigned short* __restrict__ wb,   // [9][64][64] (row=oc, k=ci)
    const float* __restrict__ bias,
    unsigned short* __restrict__ x0g)        // [B,H,W,C] bf16
{
    __shared__ unsigned short tile[NPX*TS];  // 46.7 KB
    const int b  = blockIdx.z;
    const int h0 = blockIdx.y * 16;
    const int w0 = blockIdx.x * 16;
    const int t  = threadIdx.x;

    {
        const int pxi = t & 31, g = t >> 5;
        for (int px = pxi; px < NPX; px += 32) {
            int th = px / 18, tw = px - th*18;
            int gh = h0 + th - 1, gw = w0 + tw - 1;
            short8 v = {0,0,0,0,0,0,0,0};
            if ((unsigned)gh < HH && (unsigned)gw < WW) {
                const float* sp = x + ((size_t)(b*C + g*8)*HW + gh*WW + gw);
#pragma unroll
                for (int k = 0; k < 8; ++k) v[k] = (short)f2bf(sp[k*HW]);
            }
            *(short8*)&tile[px*TS + g*8] = v;
        }
    }
    __syncthreads();

    const int wid = t >> 6, ln = t & 63;
    const int l15 = ln & 15, q = ln >> 4;

    f32x4 acc[4][4];   // [nt(pixel rows)][mt(oc)]
#pragma unroll
    for (int nt = 0; nt < 4; ++nt)
#pragma unroll
        for (int mt = 0; mt < 4; ++mt) acc[nt][mt] = (f32x4){0.f,0.f,0.f,0.f};

#pragma unroll
    for (int p = 0; p < 9; ++p) {
        const int dh = p / 3, dw = p % 3;
#pragma unroll
        for (int ks = 0; ks < 2; ++ks) {
            short8 af[4];   // weights: A[m=oc][k=ci]
#pragma unroll
            for (int mt = 0; mt < 4; ++mt)
                af[mt] = *(const short8*)&wb[((size_t)(p*C) + mt*16 + l15)*C + ks*32 + q*8];
            short8 bf[4];   // pixels: B[k=ci][n=px]
#pragma unroll
            for (int nt = 0; nt < 4; ++nt)
                bf[nt] = *(const short8*)&tile[((wid*4+nt+dh)*18 + l15 + dw)*TS + ks*32 + q*8];
#pragma unroll
            for (int nt = 0; nt < 4; ++nt)
#pragma unroll
                for (int mt = 0; mt < 4; ++mt)
                    acc[nt][mt] = __builtin_amdgcn_mfma_f32_16x16x32_bf16(
                        af[mt], bf[nt], acc[nt][mt], 0, 0, 0);
        }
    }

    // epilogue: col=pixel(l15), row=oc(q*4+reg) -> NHWC dwordx2 stores
#pragma unroll
    for (int nt = 0; nt < 4; ++nt) {
        const int hh = h0 + wid*4 + nt;
        const size_t base = ((size_t)(b*HW) + hh*WW + w0 + l15)*C;
#pragma unroll
        for (int mt = 0; mt < 4; ++mt) {
            const int oc0 = mt*16 + q*4;
            const float4 bv = *(const float4*)&bias[oc0];
            unsigned u0 = (unsigned)f2bf(acc[nt][mt][0] + bv.x)
                        | ((unsigned)f2bf(acc[nt][mt][1] + bv.y) << 16);
            unsigned u1 = (unsigned)f2bf(acc[nt][mt][2] + bv.z)
                        | ((unsigned)f2bf(acc[nt][mt][3] + bv.w) << 16);
            uint2 uu; uu.x = u0; uu.y = u1;
            *(uint2*)&x0g[base + oc0] = uu;
        }
    }
}

// ---------------------------------------------------------------------------
// Per-(b,c) spatial mean of x0 (NHWC bf16). 128 blocks, atomicAdd partials.
// ---------------------------------------------------------------------------
__global__ __launch_bounds__(256) void mean_kernel(
    const unsigned short* __restrict__ x0, float* __restrict__ m)
{
    const int b = blockIdx.x >> 4, slice = blockIdx.x & 15;
    const int t = threadIdx.x;
    const int pxi = t >> 3, g = t & 7;
    const unsigned short* base = x0 + ((size_t)b*HW + slice*1024)*C + g*8;
    float s[8];
#pragma unroll
    for (int k = 0; k < 8; ++k) s[k] = 0.f;
    for (int it = 0; it < 32; ++it) {
        short8 v = *(const short8*)&base[(size_t)(it*32 + pxi)*C];
#pragma unroll
        for (int k = 0; k < 8; ++k) s[k] += bf2f((unsigned short)v[k]);
    }
    __shared__ float red[32][64];
#pragma unroll
    for (int k = 0; k < 8; ++k) red[pxi][g*8+k] = s[k];
    __syncthreads();
    if (t < 64) {
        float acc = 0.f;
        for (int i = 0; i < 32; ++i) acc += red[i][t];
        atomicAdd(&m[b*C + t], acc * (1.f/(float)HW));
    }
}

// ---------------------------------------------------------------------------
// dw_eca: depthwise 3x3 + ECA attention, LDS-free, one thread per pixel.
// Reads x0 NHWC (L1/L2-served), writes aout NHWC bf16.
// ---------------------------------------------------------------------------
__global__ __launch_bounds__(256, 4) void dw_eca_kernel(
    const unsigned short* __restrict__ x0,
    const float* __restrict__ w1, const float* __restrict__ b1,
    const float* __restrict__ w2, const float* __restrict__ b2,
    const float* __restrict__ m,
    unsigned short* __restrict__ aout)
{
    const int tg = blockIdx.x * 256 + threadIdx.x;
    const int b = tg >> 14, px = tg & 16383;
    const int h = px >> 7, w = px & 127;
    const unsigned short* xb = x0 + (size_t)(b*HW)*C;
    const float w2a = w2[0], w2b = w2[1], w2c = w2[2], b2v = b2[0];

#pragma unroll
    for (int g = 0; g < 8; ++g) {
        float dw8[8];
#pragma unroll
        for (int k = 0; k < 8; ++k) dw8[k] = 0.f;
#pragma unroll
        for (int j = 0; j < 9; ++j) {
            const int nh = h + j/3 - 1, nw = w + j%3 - 1;
            short8 v = {0,0,0,0,0,0,0,0};
            if ((unsigned)nh < HH && (unsigned)nw < WW)
                v = *(const short8*)&xb[(size_t)(nh*WW + nw)*C + g*8];
#pragma unroll
            for (int k = 0; k < 8; ++k)
                dw8[k] = fmaf(w1[(g*8+k)*9 + j], bf2f((unsigned short)v[k]), dw8[k]);
        }
        short8 o;
#pragma unroll
        for (int k = 0; k < 8; ++k) {
            const int c = g*8 + k;
            const float mc = m[b*C + c];
            const float mp = (c > 0)  ? m[b*C + c - 1] : 0.f;
            const float mn = (c < 63) ? m[b*C + c + 1] : 0.f;
            const float att = fmaf(w2a, mp, fmaf(w2b, mc, fmaf(w2c, mn, b2v)));
            o[k] = (short)f2bf(dw8[k] + b1[c] + att);
        }
        *(short8*)&aout[(size_t)(b*HW + px)*C + g*8] = o;
    }
}

// ---------------------------------------------------------------------------
// dynconv: transposed GEMM (M=576 filter rows, N=256 pixels, K=64) + per-pixel
// dynamic conv + leaky. A=wb3 (global/L2), B=aout (global), patches from x0
// tile (LDS). og OUTER / j INNER: only one oc-group's yac (16 f32) is live
// across the tap loop -> ~85 live regs, no spill.
// ---------------------------------------------------------------------------
__global__ __launch_bounds__(256) void dynconv_kernel(
    const unsigned short* __restrict__ x0,
    const unsigned short* __restrict__ aout,
    const unsigned short* __restrict__ wb3,  // [(j*64+oc)][k]
    const float* __restrict__ b3r,           // [j*64+oc]
    unsigned short* __restrict__ yg)
{
    __shared__ unsigned short tile[NPX*TS];
    const int b  = blockIdx.z;
    const int h0 = blockIdx.y * 16;
    const int w0 = blockIdx.x * 16;
    const int t  = threadIdx.x;

    {
        const int pxi = t & 31, g = t >> 5;
        for (int px = pxi; px < NPX; px += 32) {
            int th = px / 18, tw = px - th*18;
            int gh = h0 + th - 1, gw = w0 + tw - 1;
            short8 v = {0,0,0,0,0,0,0,0};
            if ((unsigned)gh < HH && (unsigned)gw < WW)
                v = *(const short8*)&x0[((size_t)(b*HW) + gh*WW + gw)*C + g*8];
            *(short8*)&tile[px*TS + g*8] = v;
        }
    }
    __syncthreads();

    const int wid = t >> 6, ln = t & 63;
    const int l15 = ln & 15, q = ln >> 4;
    const int rl0 = wid*4;

    // persistent pixel B-fragments: B[k=ch][n=px], 8 consecutive ch of own pixel
    short8 pfrag[4][2];
#pragma unroll
    for (int nt = 0; nt < 4; ++nt) {
        const size_t pbase = ((size_t)(b*HW) + (h0+rl0+nt)*WW + w0 + l15)*C;
#pragma unroll
        for (int ks = 0; ks < 2; ++ks)
            pfrag[nt][ks] = *(const short8*)&aout[pbase + ks*32 + q*8];
    }

#pragma unroll
    for (int og = 0; og < 4; ++og) {
        f32x4 yac[4];                         // this og's accumulators only
#pragma unroll
        for (int nt = 0; nt < 4; ++nt) yac[nt] = (f32x4){0.f,0.f,0.f,0.f};

        for (int j = 0; j < 9; ++j) {         // rolled tap loop
            const int dh = j / 3, dw = j - dh*3;
            const f32x4 seed = *(const f32x4*)&b3r[j*64 + og*16 + q*4];
            const size_t abase = ((size_t)(j*64 + og*16 + l15))*C;
            const short8 a0 = *(const short8*)&wb3[abase + q*8];
            const short8 a1 = *(const short8*)&wb3[abase + 32 + q*8];
#pragma unroll
            for (int nt = 0; nt < 4; ++nt) {
                f32x4 fil = __builtin_amdgcn_mfma_f32_16x16x32_bf16(
                    a0, pfrag[nt][0], seed, 0, 0, 0);
                fil = __builtin_amdgcn_mfma_f32_16x16x32_bf16(
                    a1, pfrag[nt][1], fil, 0, 0, 0);
                const short4v pv = *(const short4v*)
                    &tile[((rl0+nt+dh)*18 + l15 + dw)*TS + og*16 + q*4];
#pragma unroll
                for (int reg = 0; reg < 4; ++reg)
                    yac[nt][reg] = fmaf(fil[reg],
                        bf2f((unsigned short)pv[reg]), yac[nt][reg]);
            }
        }

        // epilogue for this og: leaky + NHWC bf16 dwordx2 stores
#pragma unroll
        for (int nt = 0; nt < 4; ++nt) {
            const size_t base = ((size_t)(b*HW) + (h0+rl0+nt)*WW + w0 + l15)*C;
            f32x4 v = yac[nt];
#pragma unroll
            for (int reg = 0; reg < 4; ++reg)
                v[reg] = (v[reg] >= 0.f) ? v[reg] : 0.2f * v[reg];
            unsigned u0 = (unsigned)f2bf(v[0]) | ((unsigned)f2bf(v[1]) << 16);
            unsigned u1 = (unsigned)f2bf(v[2]) | ((unsigned)f2bf(v[3]) << 16);
            uint2 uu; uu.x = u0; uu.y = u1;
            *(uint2*)&yg[base + og*16 + q*4] = uu;
        }
    }
}

// ---------------------------------------------------------------------------
// convf: MFMA implicit-GEMM (M=pixels, N=oc). In: y bf16 NHWC.
// Out: fp32 NCHW (+bias+residual) via float4 stores.
// ---------------------------------------------------------------------------
__global__ __launch_bounds__(256) void convf_kernel(
    const unsigned short* __restrict__ yg,
    const unsigned short* __restrict__ wb,   // [9][64][64]
    const float* __restrict__ bias,
    const float* __restrict__ res,
    float* __restrict__ outg)
{
    __shared__ unsigned short tile[NPX*TS];
    const int b  = blockIdx.z;
    const int h0 = blockIdx.y * 16;
    const int w0 = blockIdx.x * 16;
    const int t  = threadIdx.x;

    {
        const int pxi = t & 31, g = t >> 5;
        for (int px = pxi; px < NPX; px += 32) {
            int th = px / 18, tw = px - th*18;
            int gh = h0 + th - 1, gw = w0 + tw - 1;
            short8 v = {0,0,0,0,0,0,0,0};
            if ((unsigned)gh < HH && (unsigned)gw < WW)
                v = *(const short8*)&yg[((size_t)(b*HW) + gh*WW + gw)*C + g*8];
            *(short8*)&tile[px*TS + g*8] = v;
        }
    }
    __syncthreads();

    const int wid = t >> 6, ln = t & 63;
    const int l15 = ln & 15, q = ln >> 4;

    f32x4 acc[4][4];   // [mg(pixel rows)][nt(oc)]
#pragma unroll
    for (int mg = 0; mg < 4; ++mg)
#pragma unroll
        for (int nt = 0; nt < 4; ++nt) acc[mg][nt] = (f32x4){0.f,0.f,0.f,0.f};

#pragma unroll
    for (int p = 0; p < 9; ++p) {
        const int dh = p / 3, dw = p % 3;
#pragma unroll
        for (int ks = 0; ks < 2; ++ks) {
            short8 bfrag[4];
#pragma unroll
            for (int nt = 0; nt < 4; ++nt)
                bfrag[nt] = *(const short8*)&wb[((size_t)(p*C) + nt*16 + l15)*C + ks*32 + q*8];
            short8 afrag[4];
#pragma unroll
            for (int mg = 0; mg < 4; ++mg)
                afrag[mg] = *(const short8*)&tile[((wid*4+mg+dh)*18 + l15 + dw)*TS + ks*32 + q*8];
#pragma unroll
            for (int mg = 0; mg < 4; ++mg)
#pragma unroll
                for (int nt = 0; nt < 4; ++nt)
                    acc[mg][nt] = __builtin_amdgcn_mfma_f32_16x16x32_bf16(
                        afrag[mg], bfrag[nt], acc[mg][nt], 0, 0, 0);
        }
    }

#pragma unroll
    for (int mg = 0; mg < 4; ++mg) {
        const int hh = h0 + wid*4 + mg;
#pragma unroll
        for (int nt = 0; nt < 4; ++nt) {
            const int oc = nt*16 + l15;
            const float bv = bias[oc];
            const size_t base = (size_t)(b*C + oc)*HW + hh*WW + w0 + q*4;
            const float4 rv = *(const float4*)&res[base];
            float4 ov;
            ov.x = acc[mg][nt][0] + bv + rv.x;
            ov.y = acc[mg][nt][1] + bv + rv.y;
            ov.z = acc[mg][nt][2] + bv + rv.z;
            ov.w = acc[mg][nt][3] + bv + rv.w;
            *(float4*)&outg[base] = ov;
        }
    }
}

extern "C" void kernel_launch(void* const* d_in, const int* in_sizes, int n_in,
                              void* d_out, int out_size, void* d_ws, size_t ws_size,
                              hipStream_t stream) {
    const float* x  = (const float*)d_in[0];
    const float* w0 = (const float*)d_in[1];
    const float* b0 = (const float*)d_in[2];
    const float* w1 = (const float*)d_in[3];
    const float* b1 = (const float*)d_in[4];
    const float* w2 = (const float*)d_in[5];
    const float* b2 = (const float*)d_in[6];
    const float* w3 = (const float*)d_in[7];
    const float* b3 = (const float*)d_in[8];
    const float* wf = (const float*)d_in[9];
    const float* bf = (const float*)d_in[10];
    float* out = (float*)d_out;

    unsigned short* x0  = (unsigned short*)d_ws;            // [B,H,W,C] bf16
    unsigned short* y   = x0  + (size_t)BB*HW*C;            // [B,H,W,C] bf16
    unsigned short* ao  = y   + (size_t)BB*HW*C;            // [B,H,W,C] bf16
    float*          m   = (float*)(ao + (size_t)BB*HW*C);   // [B*C]
    unsigned short* wb0 = (unsigned short*)(m + BB*C);
    unsigned short* wbf = wb0 + 9*C*C;
    unsigned short* wb3 = wbf + 9*C*C;
    float*          b3r = (float*)(wb3 + 9*C*C);

    prep_kernel<<<32, 256, 0, stream>>>(w0, wf, w3, b3, wb0, wbf, wb3, b3r, m);
    conv0_kernel<<<dim3(8,8,8), 256, 0, stream>>>(x, wb0, b0, x0);
    mean_kernel<<<128, 256, 0, stream>>>(x0, m);
    dw_eca_kernel<<<512, 256, 0, stream>>>(x0, w1, b1, w2, b2, m, ao);
    dynconv_kernel<<<dim3(8,8,8), 256, 0, stream>>>(x0, ao, wb3, b3r, y);
    convf_kernel<<<dim3(8,8,8), 256, 0, stream>>>(y, wbf, bf, x, out);
}

// Round 7
// 246.529 us; speedup vs baseline: 1.4728x; 1.0250x over previous
//
#include <hip/hip_runtime.h>

#define BB 8
#define C 64
#define HH 128
#define WW 128
#define HW (HH*WW)

#define TS 72        // LDS channel stride (ushorts): 144B rows; stride ≡ 4 mod 32
                     // dwords -> b128 lanes land in disjoint 4-bank windows (no conflict)
#define NPX 324      // 18*18 halo tile pixels

typedef __attribute__((ext_vector_type(8))) short short8;
typedef __attribute__((ext_vector_type(4))) short short4v;
typedef __attribute__((ext_vector_type(4))) float f32x4;

__device__ inline unsigned short f2bf(float f) {
    union { float f; unsigned u; } v; v.f = f;
    unsigned r = v.u + 0x7fff + ((v.u >> 16) & 1);   // RNE
    return (unsigned short)(r >> 16);
}
__device__ inline float bf2f(unsigned short h) {
    union { unsigned u; float f; } v; v.u = ((unsigned)h) << 16;
    return v.f;
}

// ---------------------------------------------------------------------------
// Prep: wb[p][row][ci] bf16 for conv0/convf (row=oc) and wb3 (row'=j*64+oc);
// b3r[j][oc]; zero m.
// ---------------------------------------------------------------------------
__global__ __launch_bounds__(256) void prep_kernel(
    const float* __restrict__ w0, const float* __restrict__ wf,
    const float* __restrict__ w3, const float* __restrict__ b3,
    unsigned short* __restrict__ wb0, unsigned short* __restrict__ wbf,
    unsigned short* __restrict__ wb3, float* __restrict__ b3r,
    float* __restrict__ m)
{
    const int t = blockIdx.x * 256 + threadIdx.x;
    for (int i = t; i < C*C*9; i += 32*256) {
        int p = i % 9; int rest = i / 9; int ci = rest % C; int oc = rest / C;
        wb0[(p*C + oc)*C + ci] = f2bf(w0[i]);
        wbf[(p*C + oc)*C + ci] = f2bf(wf[i]);
    }
    for (int i = t; i < 9*C*C; i += 32*256) {        // dst: ((j*64+oc)*64+k)
        int j = i >> 12, oc = (i >> 6) & 63, k = i & 63;
        wb3[i] = f2bf(w3[(oc*9 + j)*C + k]);
    }
    for (int i = t; i < 9*C; i += 32*256) {          // b3r[j*64+oc] = b3[oc*9+j]
        int j = i >> 6, oc = i & 63;
        b3r[i] = b3[oc*9 + j];
    }
    for (int i = t; i < BB*C; i += 32*256) m[i] = 0.f;
}

// ---------------------------------------------------------------------------
// conv0: MFMA implicit-GEMM, TRANSPOSED (M=oc, N=pixels). In: x fp32 NCHW.
// Out: x0 bf16 NHWC (+bias). 512 threads: 8 waves x 2 pixel-rows each
// (16 waves/CU vs 8 -> hides staging/K-loop latency).
// ---------------------------------------------------------------------------
__global__ __launch_bounds__(512) void conv0_kernel(
    const float* __restrict__ x,
    const unsigned short* __restrict__ wb,   // [9][64][64] (row=oc, k=ci)
    const float* __restrict__ bias,
    unsigned short* __restrict__ x0g)        // [B,H,W,C] bf16
{
    __shared__ unsigned short tile[NPX*TS];  // 46.7 KB
    const int b  = blockIdx.z;
    const int h0 = blockIdx.y * 16;
    const int w0 = blockIdx.x * 16;
    const int t  = threadIdx.x;

    {
        const int pxi = t & 63, g = t >> 6;          // g = channel octet 0..7
        for (int px = pxi; px < NPX; px += 64) {
            int th = px / 18, tw = px - th*18;
            int gh = h0 + th - 1, gw = w0 + tw - 1;
            short8 v = {0,0,0,0,0,0,0,0};
            if ((unsigned)gh < HH && (unsigned)gw < WW) {
                const float* sp = x + ((size_t)(b*C + g*8)*HW + gh*WW + gw);
#pragma unroll
                for (int k = 0; k < 8; ++k) v[k] = (short)f2bf(sp[k*HW]);
            }
            *(short8*)&tile[px*TS + g*8] = v;
        }
    }
    __syncthreads();

    const int wid = t >> 6, ln = t & 63;
    const int l15 = ln & 15, q = ln >> 4;

    f32x4 acc[2][4];   // [nt(pixel rows)][mt(oc)]
#pragma unroll
    for (int nt = 0; nt < 2; ++nt)
#pragma unroll
        for (int mt = 0; mt < 4; ++mt) acc[nt][mt] = (f32x4){0.f,0.f,0.f,0.f};

#pragma unroll
    for (int p = 0; p < 9; ++p) {
        const int dh = p / 3, dw = p % 3;
#pragma unroll
        for (int ks = 0; ks < 2; ++ks) {
            short8 af[4];   // weights: A[m=oc][k=ci]
#pragma unroll
            for (int mt = 0; mt < 4; ++mt)
                af[mt] = *(const short8*)&wb[((size_t)(p*C) + mt*16 + l15)*C + ks*32 + q*8];
            short8 bf[2];   // pixels: B[k=ci][n=px]
#pragma unroll
            for (int nt = 0; nt < 2; ++nt)
                bf[nt] = *(const short8*)&tile[((wid*2+nt+dh)*18 + l15 + dw)*TS + ks*32 + q*8];
#pragma unroll
            for (int nt = 0; nt < 2; ++nt)
#pragma unroll
                for (int mt = 0; mt < 4; ++mt)
                    acc[nt][mt] = __builtin_amdgcn_mfma_f32_16x16x32_bf16(
                        af[mt], bf[nt], acc[nt][mt], 0, 0, 0);
        }
    }

    // epilogue: col=pixel(l15), row=oc(q*4+reg) -> NHWC dwordx2 stores
#pragma unroll
    for (int nt = 0; nt < 2; ++nt) {
        const int hh = h0 + wid*2 + nt;
        const size_t base = ((size_t)(b*HW) + hh*WW + w0 + l15)*C;
#pragma unroll
        for (int mt = 0; mt < 4; ++mt) {
            const int oc0 = mt*16 + q*4;
            const float4 bv = *(const float4*)&bias[oc0];
            unsigned u0 = (unsigned)f2bf(acc[nt][mt][0] + bv.x)
                        | ((unsigned)f2bf(acc[nt][mt][1] + bv.y) << 16);
            unsigned u1 = (unsigned)f2bf(acc[nt][mt][2] + bv.z)
                        | ((unsigned)f2bf(acc[nt][mt][3] + bv.w) << 16);
            uint2 uu; uu.x = u0; uu.y = u1;
            *(uint2*)&x0g[base + oc0] = uu;
        }
    }
}

// ---------------------------------------------------------------------------
// Per-(b,c) spatial mean of x0 (NHWC bf16). 128 blocks, atomicAdd partials.
// ---------------------------------------------------------------------------
__global__ __launch_bounds__(256) void mean_kernel(
    const unsigned short* __restrict__ x0, float* __restrict__ m)
{
    const int b = blockIdx.x >> 4, slice = blockIdx.x & 15;
    const int t = threadIdx.x;
    const int pxi = t >> 3, g = t & 7;
    const unsigned short* base = x0 + ((size_t)b*HW + slice*1024)*C + g*8;
    float s[8];
#pragma unroll
    for (int k = 0; k < 8; ++k) s[k] = 0.f;
    for (int it = 0; it < 32; ++it) {
        short8 v = *(const short8*)&base[(size_t)(it*32 + pxi)*C];
#pragma unroll
        for (int k = 0; k < 8; ++k) s[k] += bf2f((unsigned short)v[k]);
    }
    __shared__ float red[32][64];
#pragma unroll
    for (int k = 0; k < 8; ++k) red[pxi][g*8+k] = s[k];
    __syncthreads();
    if (t < 64) {
        float acc = 0.f;
        for (int i = 0; i < 32; ++i) acc += red[i][t];
        atomicAdd(&m[b*C + t], acc * (1.f/(float)HW));
    }
}

// ---------------------------------------------------------------------------
// fused_dyn: depthwise3x3 + ECA from the resident x0 LDS tile -> packed bf16
// A-matrix in LDS (XOR-swizzled) -> MFMA dynamic-filter GEMM + per-pixel
// dynamic conv + leaky -> y NHWC bf16.
// 512 threads: phase 1 = thread (px, channel-half); phase 2 = 8 waves, each
// 4 pixel-rows x 2 oc-groups (og-outer keeps yac small: no spill).
// LDS 46.7 + 32 = 79.4 KB -> 2 blocks/CU = 16 waves/CU.
// Replaces round-6 dw_eca (101 MB HBM over-fetch) + dynconv + aout buffer.
// ---------------------------------------------------------------------------
__global__ __launch_bounds__(512) void fused_dyn_kernel(
    const unsigned short* __restrict__ x0,
    const float* __restrict__ w1, const float* __restrict__ b1,
    const float* __restrict__ w2, const float* __restrict__ b2,
    const unsigned short* __restrict__ wb3,  // [(j*64+oc)][k]
    const float* __restrict__ b3r,           // [j*64+oc]
    const float* __restrict__ m,
    unsigned short* __restrict__ yg)
{
    __shared__ unsigned short tile[NPX*TS];   // 46656 B
    __shared__ unsigned short alds[256*64];   // 32768 B  (A-matrix, swizzled)
    const int b  = blockIdx.z;
    const int h0 = blockIdx.y * 16;
    const int w0 = blockIdx.x * 16;
    const int t  = threadIdx.x;

    {
        const int pxi = t & 63, g = t >> 6;
        for (int px = pxi; px < NPX; px += 64) {
            int th = px / 18, tw = px - th*18;
            int gh = h0 + th - 1, gw = w0 + tw - 1;
            short8 v = {0,0,0,0,0,0,0,0};
            if ((unsigned)gh < HH && (unsigned)gw < WW)
                v = *(const short8*)&x0[((size_t)(b*HW) + gh*WW + gw)*C + g*8];
            *(short8*)&tile[px*TS + g*8] = v;
        }
    }
    __syncthreads();

    // ---- phase 1: depthwise + ECA for 32 channels of own pixel ----
    {
        const int px = t & 255, ghalf = t >> 8;      // ghalf: channels 0-31 / 32-63
        const int r = px >> 4, cc = px & 15;
        const unsigned short* tb = tile + (r*18 + cc)*TS;
        const float w2a = w2[0], w2b = w2[1], w2c = w2[2], b2v = b2[0];
        const int sw = px & 7;
#pragma unroll
        for (int g = 0; g < 4; ++g) {
            const int octet = ghalf*4 + g;           // wave-uniform
            float dw8[8];
#pragma unroll
            for (int k = 0; k < 8; ++k) dw8[k] = 0.f;
#pragma unroll
            for (int j = 0; j < 9; ++j) {
                short8 v = *(const short8*)&tb[((j/3)*18 + (j%3))*TS + octet*8];
#pragma unroll
                for (int k = 0; k < 8; ++k)
                    dw8[k] = fmaf(w1[(octet*8+k)*9 + j],
                                  bf2f((unsigned short)v[k]), dw8[k]);
            }
            short8 o;
#pragma unroll
            for (int k = 0; k < 8; ++k) {
                const int c = octet*8 + k;
                const float mc = m[b*C + c];
                const float mp = (c > 0)  ? m[b*C + c - 1] : 0.f;
                const float mn = (c < 63) ? m[b*C + c + 1] : 0.f;
                const float att = fmaf(w2a, mp, fmaf(w2b, mc, fmaf(w2c, mn, b2v)));
                o[k] = (short)f2bf(dw8[k] + b1[c] + att);
            }
            *(short8*)&alds[px*64 + ((octet ^ sw) * 8)] = o;
        }
    }
    __syncthreads();

    // ---- phase 2: MFMA dynamic-filter GEMM + dynamic conv ----
    const int wid = t >> 6, ln = t & 63;
    const int l15 = ln & 15, q = ln >> 4;
    const int rl0 = (wid & 3) * 4;                   // pixel-row group
    const int ogh = wid >> 2;                        // oc-half: waves 0-3 / 4-7

    short8 pfrag[4][2];                              // B[k=ch][n=px]
#pragma unroll
    for (int nt = 0; nt < 4; ++nt) {
        const int p = (rl0 + nt)*16 + l15;
        const int psw = p & 7;
#pragma unroll
        for (int ks = 0; ks < 2; ++ks)
            pfrag[nt][ks] = *(const short8*)&alds[p*64 + (((ks*4 + q) ^ psw) * 8)];
    }

#pragma unroll
    for (int ogi = 0; ogi < 2; ++ogi) {
        const int og = ogh*2 + ogi;
        f32x4 yac[4];
#pragma unroll
        for (int nt = 0; nt < 4; ++nt) yac[nt] = (f32x4){0.f,0.f,0.f,0.f};

        for (int j = 0; j < 9; ++j) {
            const int dh = j / 3, dw = j - dh*3;
            const f32x4 seed = *(const f32x4*)&b3r[j*64 + og*16 + q*4];
            const size_t abase = ((size_t)(j*64 + og*16 + l15))*C;
            const short8 a0 = *(const short8*)&wb3[abase + q*8];
            const short8 a1 = *(const short8*)&wb3[abase + 32 + q*8];
#pragma unroll
            for (int nt = 0; nt < 4; ++nt) {
                f32x4 fil = __builtin_amdgcn_mfma_f32_16x16x32_bf16(
                    a0, pfrag[nt][0], seed, 0, 0, 0);
                fil = __builtin_amdgcn_mfma_f32_16x16x32_bf16(
                    a1, pfrag[nt][1], fil, 0, 0, 0);
                const short4v pv = *(const short4v*)
                    &tile[((rl0+nt+dh)*18 + l15 + dw)*TS + og*16 + q*4];
#pragma unroll
                for (int reg = 0; reg < 4; ++reg)
                    yac[nt][reg] = fmaf(fil[reg],
                        bf2f((unsigned short)pv[reg]), yac[nt][reg]);
            }
        }

#pragma unroll
        for (int nt = 0; nt < 4; ++nt) {
            const size_t base = ((size_t)(b*HW) + (h0+rl0+nt)*WW + w0 + l15)*C;
            f32x4 v = yac[nt];
#pragma unroll
            for (int reg = 0; reg < 4; ++reg)
                v[reg] = (v[reg] >= 0.f) ? v[reg] : 0.2f * v[reg];
            unsigned u0 = (unsigned)f2bf(v[0]) | ((unsigned)f2bf(v[1]) << 16);
            unsigned u1 = (unsigned)f2bf(v[2]) | ((unsigned)f2bf(v[3]) << 16);
            uint2 uu; uu.x = u0; uu.y = u1;
            *(uint2*)&yg[base + og*16 + q*4] = uu;
        }
    }
}

// ---------------------------------------------------------------------------
// convf: MFMA implicit-GEMM (M=pixels, N=oc). In: y bf16 NHWC.
// Out: fp32 NCHW (+bias+residual) via float4 stores. 512 threads, 8 waves.
// ---------------------------------------------------------------------------
__global__ __launch_bounds__(512) void convf_kernel(
    const unsigned short* __restrict__ yg,
    const unsigned short* __restrict__ wb,   // [9][64][64]
    const float* __restrict__ bias,
    const float* __restrict__ res,
    float* __restrict__ outg)
{
    __shared__ unsigned short tile[NPX*TS];
    const int b  = blockIdx.z;
    const int h0 = blockIdx.y * 16;
    const int w0 = blockIdx.x * 16;
    const int t  = threadIdx.x;

    {
        const int pxi = t & 63, g = t >> 6;
        for (int px = pxi; px < NPX; px += 64) {
            int th = px / 18, tw = px - th*18;
            int gh = h0 + th - 1, gw = w0 + tw - 1;
            short8 v = {0,0,0,0,0,0,0,0};
            if ((unsigned)gh < HH && (unsigned)gw < WW)
                v = *(const short8*)&yg[((size_t)(b*HW) + gh*WW + gw)*C + g*8];
            *(short8*)&tile[px*TS + g*8] = v;
        }
    }
    __syncthreads();

    const int wid = t >> 6, ln = t & 63;
    const int l15 = ln & 15, q = ln >> 4;

    f32x4 acc[2][4];   // [mg(pixel rows)][nt(oc)]
#pragma unroll
    for (int mg = 0; mg < 2; ++mg)
#pragma unroll
        for (int nt = 0; nt < 4; ++nt) acc[mg][nt] = (f32x4){0.f,0.f,0.f,0.f};

#pragma unroll
    for (int p = 0; p < 9; ++p) {
        const int dh = p / 3, dw = p % 3;
#pragma unroll
        for (int ks = 0; ks < 2; ++ks) {
            short8 bfrag[4];
#pragma unroll
            for (int nt = 0; nt < 4; ++nt)
                bfrag[nt] = *(const short8*)&wb[((size_t)(p*C) + nt*16 + l15)*C + ks*32 + q*8];
            short8 afrag[2];
#pragma unroll
            for (int mg = 0; mg < 2; ++mg)
                afrag[mg] = *(const short8*)&tile[((wid*2+mg+dh)*18 + l15 + dw)*TS + ks*32 + q*8];
#pragma unroll
            for (int mg = 0; mg < 2; ++mg)
#pragma unroll
                for (int nt = 0; nt < 4; ++nt)
                    acc[mg][nt] = __builtin_amdgcn_mfma_f32_16x16x32_bf16(
                        afrag[mg], bfrag[nt], acc[mg][nt], 0, 0, 0);
        }
    }

#pragma unroll
    for (int mg = 0; mg < 2; ++mg) {
        const int hh = h0 + wid*2 + mg;
#pragma unroll
        for (int nt = 0; nt < 4; ++nt) {
            const int oc = nt*16 + l15;
            const float bv = bias[oc];
            const size_t base = (size_t)(b*C + oc)*HW + hh*WW + w0 + q*4;
            const float4 rv = *(const float4*)&res[base];
            float4 ov;
            ov.x = acc[mg][nt][0] + bv + rv.x;
            ov.y = acc[mg][nt][1] + bv + rv.y;
            ov.z = acc[mg][nt][2] + bv + rv.z;
            ov.w = acc[mg][nt][3] + bv + rv.w;
            *(float4*)&outg[base] = ov;
        }
    }
}

extern "C" void kernel_launch(void* const* d_in, const int* in_sizes, int n_in,
                              void* d_out, int out_size, void* d_ws, size_t ws_size,
                              hipStream_t stream) {
    const float* x  = (const float*)d_in[0];
    const float* w0 = (const float*)d_in[1];
    const float* b0 = (const float*)d_in[2];
    const float* w1 = (const float*)d_in[3];
    const float* b1 = (const float*)d_in[4];
    const float* w2 = (const float*)d_in[5];
    const float* b2 = (const float*)d_in[6];
    const float* w3 = (const float*)d_in[7];
    const float* b3 = (const float*)d_in[8];
    const float* wf = (const float*)d_in[9];
    const float* bf = (const float*)d_in[10];
    float* out = (float*)d_out;

    unsigned short* x0  = (unsigned short*)d_ws;            // [B,H,W,C] bf16
    unsigned short* y   = x0  + (size_t)BB*HW*C;            // [B,H,W,C] bf16
    float*          m   = (float*)(y + (size_t)BB*HW*C);    // [B*C]
    unsigned short* wb0 = (unsigned short*)(m + BB*C);
    unsigned short* wbf = wb0 + 9*C*C;
    unsigned short* wb3 = wbf + 9*C*C;
    float*          b3r = (float*)(wb3 + 9*C*C);

    prep_kernel<<<32, 256, 0, stream>>>(w0, wf, w3, b3, wb0, wbf, wb3, b3r, m);
    conv0_kernel<<<dim3(8,8,8), 512, 0, stream>>>(x, wb0, b0, x0);
    mean_kernel<<<128, 256, 0, stream>>>(x0, m);
    fused_dyn_kernel<<<dim3(8,8,8), 512, 0, stream>>>(
        x0, w1, b1, w2, b2, wb3, b3r, m, y);
    convf_kernel<<<dim3(8,8,8), 512, 0, stream>>>(y, wbf, bf, x, out);
}